// Round 1
// baseline (548.042 us; speedup 1.0000x reference)
//
#include <hip/hip_runtime.h>

#define SEQ   200
#define BATCH 1024
#define DIM   300
#define HID   600

// Kernel 1: per-batch-column dedup + embedding-bag gather for both tables.
// One block per column b (grid=1024), 128 threads (2 waves).
// hidden[b][0:300] = sum_{unique s} lut[tok], hidden[b][300:600] = static_lut sum.
__global__ __launch_bounds__(128) void embed_kernel(
    const int* __restrict__ tokens,
    const float* __restrict__ lut,
    const float* __restrict__ slut,
    float* __restrict__ hidden) {
  const int b = blockIdx.x;
  const int tid = threadIdx.x;

  __shared__ int   toks[SEQ];
  __shared__ float keep[SEQ];

  for (int s = tid; s < SEQ; s += 128) toks[s] = tokens[s * BATCH + b];
  __syncthreads();

  // first-occurrence mask: keep[s]=1 iff no p<s with toks[p]==toks[s]
  for (int s = tid; s < SEQ; s += 128) {
    const int t = toks[s];
    float m = 1.f;
    for (int p = 0; p < s; ++p) {
      if (toks[p] == t) { m = 0.f; break; }
    }
    keep[s] = m;
  }
  __syncthreads();

  // gather: threads 0..74 each own one float4 slice of the 300-float row
  if (tid < DIM / 4) {
    float4 aL = make_float4(0.f, 0.f, 0.f, 0.f);
    float4 aS = make_float4(0.f, 0.f, 0.f, 0.f);
#pragma unroll 4
    for (int s = 0; s < SEQ; ++s) {
      const float  m   = keep[s];                 // 0 or 1, branch-free
      const size_t row = (size_t)toks[s] * DIM;   // row base, 16B-aligned (1200B rows)
      const float4 vl = ((const float4*)(lut  + row))[tid];
      const float4 vs = ((const float4*)(slut + row))[tid];
      aL.x += m * vl.x; aL.y += m * vl.y; aL.z += m * vl.z; aL.w += m * vl.w;
      aS.x += m * vs.x; aS.y += m * vs.y; aS.z += m * vs.z; aS.w += m * vs.w;
    }
    float* hb = hidden + (size_t)b * HID;
    ((float4*)hb)[tid]         = aL;
    ((float4*)(hb + DIM))[tid] = aS;
  }
}

// Kernel 2: fused MLP + output reduce.
// Block = 256 threads (4 waves), handles 8 batch rows. Each wave processes
// j = wave, wave+4, ... (150 neurons). Lanes split k (coalesced W1 row reads),
// 8 simultaneous dots (one per batch), butterfly reduce, relu*W2 accumulate.
__global__ __launch_bounds__(256) void mlp_kernel(
    const float* __restrict__ hidden,
    const float* __restrict__ W1,
    const float* __restrict__ b1,
    const float* __restrict__ W2,
    const float* __restrict__ b2,
    float* __restrict__ out) {
  const int bb0  = blockIdx.x * 8;
  const int tid  = threadIdx.x;
  const int wave = tid >> 6;
  const int lane = tid & 63;

  __shared__ float hid[8][HID];   // 19.2 KB
  __shared__ float wacc[4][8];

  for (int i = tid; i < 8 * HID; i += 256) {
    const int bb = i / HID, k = i % HID;
    hid[bb][k] = hidden[(size_t)(bb0 + bb) * HID + k];
  }
  __syncthreads();

  float acc = 0.f;  // lanes 0..7 accumulate out for batch (bb0+lane)

  for (int j = wave; j < HID; j += 4) {
    const float b1j = b1[j];
    const float w2j = W2[j];
    float dot0 = 0.f, dot1 = 0.f, dot2 = 0.f, dot3 = 0.f;
    float dot4 = 0.f, dot5 = 0.f, dot6 = 0.f, dot7 = 0.f;
    for (int k = lane; k < HID; k += 64) {
      const float w = W1[(size_t)j * HID + k];   // coalesced, L2-resident
      dot0 += hid[0][k] * w;
      dot1 += hid[1][k] * w;
      dot2 += hid[2][k] * w;
      dot3 += hid[3][k] * w;
      dot4 += hid[4][k] * w;
      dot5 += hid[5][k] * w;
      dot6 += hid[6][k] * w;
      dot7 += hid[7][k] * w;
    }
#define REDUCE_ONE(D, BB)                                          \
    {                                                              \
      float v = (D);                                               \
      v += __shfl_xor(v, 32); v += __shfl_xor(v, 16);              \
      v += __shfl_xor(v, 8);  v += __shfl_xor(v, 4);               \
      v += __shfl_xor(v, 2);  v += __shfl_xor(v, 1);               \
      if (lane == (BB)) {                                          \
        const float h = v + b1j;                                   \
        acc += (h > 0.f ? h : 0.f) * w2j;                          \
      }                                                            \
    }
    REDUCE_ONE(dot0, 0) REDUCE_ONE(dot1, 1) REDUCE_ONE(dot2, 2)
    REDUCE_ONE(dot3, 3) REDUCE_ONE(dot4, 4) REDUCE_ONE(dot5, 5)
    REDUCE_ONE(dot6, 6) REDUCE_ONE(dot7, 7)
#undef REDUCE_ONE
  }

  if (lane < 8) wacc[wave][lane] = acc;
  __syncthreads();
  if (tid < 8) {
    out[bb0 + tid] = wacc[0][tid] + wacc[1][tid] + wacc[2][tid] +
                     wacc[3][tid] + b2[0];
  }
}

extern "C" void kernel_launch(void* const* d_in, const int* in_sizes, int n_in,
                              void* d_out, int out_size, void* d_ws, size_t ws_size,
                              hipStream_t stream) {
  const int*   tokens = (const int*)  d_in[0];
  const float* lut    = (const float*)d_in[1];
  const float* slut   = (const float*)d_in[2];
  const float* W1     = (const float*)d_in[3];
  const float* b1     = (const float*)d_in[4];
  const float* W2     = (const float*)d_in[5];
  const float* b2     = (const float*)d_in[6];
  float* out    = (float*)d_out;
  float* hidden = (float*)d_ws;   // 1024*600*4 = 2.4 MB

  embed_kernel<<<BATCH, 128, 0, stream>>>(tokens, lut, slut, hidden);
  mlp_kernel<<<BATCH / 8, 256, 0, stream>>>(hidden, W1, b1, W2, b2, out);
}

// Round 2
// 187.944 us; speedup vs baseline: 2.9160x; 2.9160x over previous
//
#include <hip/hip_runtime.h>

#define SEQ   200
#define BATCH 1024
#define DIM   300
#define HID   600

// ---------------- Kernel 1: dedup + embedding-bag gather ----------------
// One block per batch column. 256 threads: tid 0..74 gather lut slices,
// tid 128..202 gather static_lut slices (independent wave groups -> 2x MLP
// memory-level parallelism vs one group doing both tables).
__global__ __launch_bounds__(256) void embed_kernel(
    const int* __restrict__ tokens,
    const float* __restrict__ lut,
    const float* __restrict__ slut,
    float* __restrict__ hidden) {
  const int b = blockIdx.x;
  const int tid = threadIdx.x;

  __shared__ int   toks[SEQ];
  __shared__ float keep[SEQ];

  for (int s = tid; s < SEQ; s += 256) toks[s] = tokens[s * BATCH + b];
  __syncthreads();

  for (int s = tid; s < SEQ; s += 256) {
    const int t = toks[s];
    float m = 1.f;
    for (int p = 0; p < s; ++p) {
      if (toks[p] == t) { m = 0.f; break; }
    }
    keep[s] = m;
  }
  __syncthreads();

  const int grp  = tid >> 7;    // 0 -> lut, 1 -> static_lut
  const int slot = tid & 127;   // float4 slice within the 300-float row
  if (slot < DIM / 4) {
    const float* __restrict__ tab = grp ? slut : lut;
    float4 a = make_float4(0.f, 0.f, 0.f, 0.f);
#pragma unroll 8
    for (int s = 0; s < SEQ; ++s) {
      const float  m = keep[s];                       // 0/1, branch-free
      const float4 v = ((const float4*)(tab + (size_t)toks[s] * DIM))[slot];
      a.x += m * v.x; a.y += m * v.y; a.z += m * v.z; a.w += m * v.w;
    }
    float* hb = hidden + (size_t)b * HID + grp * DIM;
    ((float4*)hb)[slot] = a;
  }
}

// ---------------- Kernel 2a: out[b] = b2 (blocks of kernel 2b race-add) ----
__global__ __launch_bounds__(256) void out_init_kernel(
    float* __restrict__ out, const float* __restrict__ b2) {
  const int i = blockIdx.x * 256 + threadIdx.x;
  if (i < BATCH) out[i] = b2[0];
}

// ---------------- Kernel 2b: tiled fp32 GEMM + fused relu*W2 reduce -------
// Tile: BM=64 batches x BN=64 neurons, BK=60. 256 threads, each owns a
// 4x4 register tile (16 independent FMAs/k -> no cross-lane reduce in the
// hot loop). Grid (16, 10). Per-j relu*W2 folded per-thread, then one LDS
// reduce over the 16 j-groups and atomicAdd into out.
#define BM   64
#define BN   64
#define BK   60
#define KPAD 61
#define JPAD 68

__global__ __launch_bounds__(256) void mlp_kernel(
    const float* __restrict__ hidden,
    const float* __restrict__ W1,
    const float* __restrict__ b1,
    const float* __restrict__ W2,
    float* __restrict__ out) {
  const int b0  = blockIdx.x * BM;
  const int j0  = blockIdx.y * BN;
  const int tid = threadIdx.x;
  const int jt  = tid & 15;    // 16 j-groups of 4 neurons
  const int bt  = tid >> 4;    // 16 b-groups of 4 batches

  __shared__ float As[BM][KPAD];   // hidden tile, row-major [b][k]
  __shared__ float Bs[BK][JPAD];   // W1 tile, transposed   [k][j]
  __shared__ float red[BM][17];    // [b][jt] reduction scratch

  float acc[4][4] = {};            // [bb][jj]

  for (int kt = 0; kt < HID; kt += BK) {
    for (int i = tid; i < BM * BK; i += 256) {
      const int bb = i / BK, kk = i % BK;
      As[bb][kk] = hidden[(size_t)(b0 + bb) * HID + kt + kk];
    }
    for (int i = tid; i < BN * BK; i += 256) {
      const int jj = i / BK, kk = i % BK;
      const int j  = j0 + jj;
      Bs[kk][jj] = (j < HID) ? W1[(size_t)j * HID + kt + kk] : 0.f;
    }
    __syncthreads();

#pragma unroll 4
    for (int k = 0; k < BK; ++k) {
      const float4 bv = *(const float4*)&Bs[k][jt * 4];
      const float a0 = As[bt * 4 + 0][k];
      const float a1 = As[bt * 4 + 1][k];
      const float a2 = As[bt * 4 + 2][k];
      const float a3 = As[bt * 4 + 3][k];
      acc[0][0] += a0 * bv.x; acc[0][1] += a0 * bv.y;
      acc[0][2] += a0 * bv.z; acc[0][3] += a0 * bv.w;
      acc[1][0] += a1 * bv.x; acc[1][1] += a1 * bv.y;
      acc[1][2] += a1 * bv.z; acc[1][3] += a1 * bv.w;
      acc[2][0] += a2 * bv.x; acc[2][1] += a2 * bv.y;
      acc[2][2] += a2 * bv.z; acc[2][3] += a2 * bv.w;
      acc[3][0] += a3 * bv.x; acc[3][1] += a3 * bv.y;
      acc[3][2] += a3 * bv.z; acc[3][3] += a3 * bv.w;
    }
    __syncthreads();
  }

  // epilogue: fold relu(h+b1)*W2 over this thread's 4 j's
  float part[4] = {0.f, 0.f, 0.f, 0.f};
#pragma unroll
  for (int jj = 0; jj < 4; ++jj) {
    const int j = j0 + jt * 4 + jj;
    if (j < HID) {
      const float b1j = b1[j];
      const float w2j = W2[j];
#pragma unroll
      for (int bb = 0; bb < 4; ++bb) {
        const float h = acc[bb][jj] + b1j;
        part[bb] += (h > 0.f ? h : 0.f) * w2j;
      }
    }
  }
#pragma unroll
  for (int bb = 0; bb < 4; ++bb) red[bt * 4 + bb][jt] = part[bb];
  __syncthreads();

  if (tid < BM) {
    float s = 0.f;
#pragma unroll
    for (int q = 0; q < 16; ++q) s += red[tid][q];
    atomicAdd(&out[b0 + tid], s);
  }
}

extern "C" void kernel_launch(void* const* d_in, const int* in_sizes, int n_in,
                              void* d_out, int out_size, void* d_ws, size_t ws_size,
                              hipStream_t stream) {
  const int*   tokens = (const int*)  d_in[0];
  const float* lut    = (const float*)d_in[1];
  const float* slut   = (const float*)d_in[2];
  const float* W1     = (const float*)d_in[3];
  const float* b1     = (const float*)d_in[4];
  const float* W2     = (const float*)d_in[5];
  const float* b2     = (const float*)d_in[6];
  float* out    = (float*)d_out;
  float* hidden = (float*)d_ws;   // 1024*600*4 = 2.4 MB

  out_init_kernel<<<(BATCH + 255) / 256, 256, 0, stream>>>(out, b2);
  embed_kernel<<<BATCH, 256, 0, stream>>>(tokens, lut, slut, hidden);
  mlp_kernel<<<dim3(BATCH / BM, (HID + BN - 1) / BN), 256, 0, stream>>>(
      hidden, W1, b1, W2, out);
}

// Round 4
// 162.089 us; speedup vs baseline: 3.3811x; 1.1595x over previous
//
#include <hip/hip_runtime.h>

#define SEQ   200
#define BATCH 1024
#define DIM   300
#define HID   600
#define JC    4            // j-chunks across blockIdx.y
#define JPER  (HID / JC)   // 150 j per chunk
#define JT    10           // j-tile: 150 = 15 * 10

// ---------------- Kernel 1: dedup + embedding-bag gather ----------------
// One block per batch column. tid 0..74 gather lut float4 slices,
// tid 128..202 gather static_lut slices.
__global__ __launch_bounds__(256) void embed_kernel(
    const int* __restrict__ tokens,
    const float* __restrict__ lut,
    const float* __restrict__ slut,
    float* __restrict__ hidden) {
  const int b = blockIdx.x;
  const int tid = threadIdx.x;

  __shared__ int   toks[SEQ];
  __shared__ float keep[SEQ];

  for (int s = tid; s < SEQ; s += 256) toks[s] = tokens[s * BATCH + b];
  __syncthreads();

  for (int s = tid; s < SEQ; s += 256) {
    const int t = toks[s];
    float m = 1.f;
    for (int p = 0; p < s; ++p) {
      if (toks[p] == t) { m = 0.f; break; }
    }
    keep[s] = m;
  }
  __syncthreads();

  const int grp  = tid >> 7;    // 0 -> lut, 1 -> static_lut
  const int slot = tid & 127;   // float4 slice within the 300-float row
  if (slot < DIM / 4) {
    const float* __restrict__ tab = grp ? slut : lut;
    float4 a = make_float4(0.f, 0.f, 0.f, 0.f);
#pragma unroll 8
    for (int s = 0; s < SEQ; ++s) {
      const float  m = keep[s];                       // 0/1, branch-free
      const float4 v = ((const float4*)(tab + (size_t)toks[s] * DIM))[slot];
      a.x += m * v.x; a.y += m * v.y; a.z += m * v.z; a.w += m * v.w;
    }
    float* hb = hidden + (size_t)b * HID + grp * DIM;
    ((float4*)hb)[slot] = a;
  }
}

// ---------------- Kernel 2a: out[b] = b2 (mlp blocks atomic-add) --------
__global__ __launch_bounds__(256) void out_init_kernel(
    float* __restrict__ out, const float* __restrict__ b2) {
  const int i = blockIdx.x * 256 + threadIdx.x;
  if (i < BATCH) out[i] = b2[0];
}

// ---------------- Kernel 2b: MLP, zero-LDS wave-dot + DPP reduce ---------
// Wave = one batch row; lanes split k. hidden row cached in 10 VGPRs.
// W1 rows read coalesced from L2 (identical addresses across the block's
// 4 waves -> L1 reuse). Dot reduced with 6 DPP adds (no LDS traffic);
// lane 63 folds relu(h+b1)*W2 and atomicAdds per wave.
template <int CTRL>
__device__ __forceinline__ float dpp_add(float x) {
  const int y = __builtin_amdgcn_update_dpp(
      0, __float_as_int(x), CTRL, 0xf, 0xf, true);
  return x + __int_as_float(y);
}

__global__ __launch_bounds__(256) void mlp_kernel(
    const float* __restrict__ hidden,
    const float* __restrict__ W1,
    const float* __restrict__ b1,
    const float* __restrict__ W2,
    float* __restrict__ out) {
  const int wave = threadIdx.x >> 6;
  const int lane = threadIdx.x & 63;
  const int b    = blockIdx.x * 4 + wave;
  const int j0   = blockIdx.y * JPER;

  // preload hidden row: k = lane + 64*i  (600 = 64*9 + 24)
  float a[10];
  const float* __restrict__ hb = hidden + (size_t)b * HID;
#pragma unroll
  for (int i = 0; i < 9; ++i) a[i] = hb[lane + 64 * i];
  a[9] = (lane < 24) ? hb[lane + 576] : 0.f;

  float acc = 0.f;

  for (int jg = 0; jg < JPER; jg += JT) {
    float dot[JT];
#pragma unroll
    for (int jj = 0; jj < JT; ++jj) dot[jj] = 0.f;

#pragma unroll
    for (int jj = 0; jj < JT; ++jj) {
      const float* __restrict__ wr = W1 + (size_t)(j0 + jg + jj) * HID;
#pragma unroll
      for (int i = 0; i < 9; ++i) dot[jj] += a[i] * wr[lane + 64 * i];
      dot[jj] += (lane < 24) ? a[9] * wr[lane + 576] : 0.f;
    }

#pragma unroll
    for (int jj = 0; jj < JT; ++jj) {
      float h = dot[jj];
      h = dpp_add<0x111>(h);   // row_shr:1
      h = dpp_add<0x112>(h);   // row_shr:2
      h = dpp_add<0x114>(h);   // row_shr:4
      h = dpp_add<0x118>(h);   // row_shr:8
      h = dpp_add<0x142>(h);   // row_bcast:15
      h = dpp_add<0x143>(h);   // row_bcast:31  -> lane 63 = full sum
      const int j = j0 + jg + jj;
      const float r = fmaxf(h + b1[j], 0.f) * W2[j];
      if (lane == 63) acc += r;
    }
  }

  if (lane == 63) atomicAdd(&out[b], acc);
}

extern "C" void kernel_launch(void* const* d_in, const int* in_sizes, int n_in,
                              void* d_out, int out_size, void* d_ws, size_t ws_size,
                              hipStream_t stream) {
  const int*   tokens = (const int*)  d_in[0];
  const float* lut    = (const float*)d_in[1];
  const float* slut   = (const float*)d_in[2];
  const float* W1     = (const float*)d_in[3];
  const float* b1     = (const float*)d_in[4];
  const float* W2     = (const float*)d_in[5];
  const float* b2     = (const float*)d_in[6];
  float* out    = (float*)d_out;
  float* hidden = (float*)d_ws;   // 1024*600*4 = 2.4 MB

  out_init_kernel<<<(BATCH + 255) / 256, 256, 0, stream>>>(out, b2);
  embed_kernel<<<BATCH, 256, 0, stream>>>(tokens, lut, slut, hidden);
  mlp_kernel<<<dim3(BATCH / 4, JC), 256, 0, stream>>>(hidden, W1, b1, W2, out);
}